// Round 3
// baseline (495.931 us; speedup 1.0000x reference)
//
#include <hip/hip_runtime.h>

// NeRF volume rendering — ONE THREAD PER RAY, streaming alpha compositing.
// Zero cross-lane ops; implements the reference recurrence exactly:
//   T=1; per sample: alpha=1-exp(-relu(sigma)*delta); w=T*alpha;
//   accumulate rgb/depth; T *= (exp_term + 1e-10).
// Per-lane loads are 512B-strided dwordx4, but the unrolled loop consumes
// every cache line fully within the wave (reuse distance 1 iter, ~8KB L1
// footprint/wave) -> HBM traffic = exact input size (~420 MB).

__global__ __launch_bounds__(256) void nerf_ray_kernel(
    const float4* __restrict__ pred4,   // [rays*32] (r,g,b,sigma logits)
    const float4* __restrict__ t4,      // [rays*8]  (32 t-values per ray)
    float* __restrict__ out_rgb,        // [rays*3]
    float* __restrict__ out_depth,      // [rays]
    int rays)
{
    const int ray = blockIdx.x * 256 + threadIdx.x;
    if (ray >= rays) return;

    // Preload all 32 t-values into registers (fully unrolled -> no scratch).
    float tt[33];
    {
        const float4* tp = t4 + (size_t)ray * 8;
        #pragma unroll
        for (int k = 0; k < 8; ++k) {
            const float4 q = tp[k];
            tt[4*k+0] = q.x; tt[4*k+1] = q.y; tt[4*k+2] = q.z; tt[4*k+3] = q.w;
        }
        tt[32] = tt[31] + 1e10f;   // makes delta[31] = 1e10 naturally
    }

    float T = 1.0f, r = 0.0f, g = 0.0f, b = 0.0f, d = 0.0f;
    const float4* pp = pred4 + (size_t)ray * 32;

    #pragma unroll
    for (int c = 0; c < 4; ++c) {
        // batch 8 pred loads so the compiler keeps them in flight together
        float4 P[8];
        #pragma unroll
        for (int k = 0; k < 8; ++k) P[k] = pp[c * 8 + k];

        #pragma unroll
        for (int k = 0; k < 8; ++k) {
            const int   j     = c * 8 + k;
            const float delta = tt[j + 1] - tt[j];
            const float sg    = fmaxf(P[k].w, 0.0f);
            const float et    = __expf(-sg * delta);    // exp_term = 1 - alpha
            const float w     = T * (1.0f - et);        // alpha * transmittance
            r += w * __builtin_amdgcn_rcpf(1.0f + __expf(-P[k].x));
            g += w * __builtin_amdgcn_rcpf(1.0f + __expf(-P[k].y));
            b += w * __builtin_amdgcn_rcpf(1.0f + __expf(-P[k].z));
            d += w * tt[j];
            T *= (et + 1e-10f);                         // exact reference update
        }
    }

    out_rgb[ray * 3 + 0] = r;
    out_rgb[ray * 3 + 1] = g;
    out_rgb[ray * 3 + 2] = b;
    out_depth[ray]       = d;
}

extern "C" void kernel_launch(void* const* d_in, const int* in_sizes, int n_in,
                              void* d_out, int out_size, void* d_ws, size_t ws_size,
                              hipStream_t stream) {
    const float4* pred4 = (const float4*)d_in[0];   // [B,H,W,32,4] f32
    const float4* t4    = (const float4*)d_in[1];   // [B,H,W,32]   f32

    const int total_samples = in_sizes[1];          // 20,480,000
    const int rays          = total_samples / 32;   // 640,000

    float* out_rgb   = (float*)d_out;
    float* out_depth = (float*)d_out + (size_t)rays * 3;

    const int block = 256;
    const int grid  = (rays + block - 1) / block;   // 2500
    nerf_ray_kernel<<<grid, block, 0, stream>>>(pred4, t4, out_rgb,
                                                out_depth, rays);
}

// Round 4
// 461.085 us; speedup vs baseline: 1.0756x; 1.0756x over previous
//
#include <hip/hip_runtime.h>

// NeRF volume rendering: one lane per sample, 32 lanes per ray (2 rays/wave).
// R4: cut DS-pipe cross-lane ops 27 -> 12 per wave vs R1:
//   - exclusive cumprod = inclusive * rcp(self)   (saves 1 shuffle)
//   - fused 4-value segment reduction in 6 shuffles (was 20) by routing
//     different variables through shared butterfly steps with lane-selects.
// Scan itself stays the R1-validated multiply-scan (exact ref semantics).

__global__ __launch_bounds__(256) void nerf_render_kernel(
    const float4* __restrict__ pred4,   // [rays*32] rgb logits + sigma
    const float*  __restrict__ tvals,   // [rays*32]
    float* __restrict__ out_rgb,        // [rays*3]
    float* __restrict__ out_depth)      // [rays]
{
    const int gid  = blockIdx.x * 256 + threadIdx.x;  // grid covers exactly
    const int l    = threadIdx.x & 31;                // lane within ray segment
    const int ray  = gid >> 5;

    const float4 p  = pred4[gid];
    const float  tv = tvals[gid];

    // delta[i] = t[i+1]-t[i], last = 1e10                       (1 shuffle)
    const float tn    = __shfl_down(tv, 1, 32);
    const float delta = (l == 31) ? 1e10f : (tn - tv);

    const float sigma = fmaxf(p.w, 0.0f);
    const float et    = __expf(-sigma * delta);   // exp_term = 1 - alpha
    const float alpha = 1.0f - et;
    const float ep    = et + 1e-10f;

    // inclusive multiply-scan over the 32-lane segment          (5 shuffles)
    float v = ep;
    #pragma unroll
    for (int off = 1; off < 32; off <<= 1) {
        const float t = __shfl_up(v, off, 32);
        v = (l >= off) ? v * t : v;
    }
    // exclusive: cp_excl = cp_incl / ep  (ep >= 1e-10; rcp err ~1e-7)
    const float T = v * __builtin_amdgcn_rcpf(ep);

    const float w = alpha * T;
    float r = w * __builtin_amdgcn_rcpf(1.0f + __expf(-p.x));
    float g = w * __builtin_amdgcn_rcpf(1.0f + __expf(-p.y));
    float b = w * __builtin_amdgcn_rcpf(1.0f + __expf(-p.z));
    float d = w * tv;

    // ---- fused 4-value segment reduction, 6 shuffles total ----
    // xor16 step (2 shuffles): consolidate r,g into lanes 0-15, b,d into 16-31
    {
        const bool hi = (l & 16) != 0;
        const float sA = hi ? r : b;          // lo lanes send b, hi send r
        const float rA = __shfl_xor(sA, 16, 32);
        if (hi) b += rA; else r += rA;
        const float sB = hi ? g : d;          // lo send d, hi send g
        const float rB = __shfl_xor(sB, 16, 32);
        if (hi) d += rB; else g += rB;
    }
    // xor8 step (1 shuffle): ownership r:0-7, g:8-15, b:16-23, d:24-31
    {
        const bool o8  = (l & 8) != 0;
        const bool o16 = (l & 16) != 0;
        const float s  = o8 ? (o16 ? b : r) : (o16 ? d : g);
        const float rc = __shfl_xor(s, 8, 32);
        if (o8) { if (o16) d += rc; else g += rc; }
        else    { if (o16) b += rc; else r += rc; }
    }
    // collapse to one register, 3 plain butterflies             (3 shuffles)
    float acc = (l & 16) ? ((l & 8) ? d : b) : ((l & 8) ? g : r);
    acc += __shfl_xor(acc, 4, 32);
    acc += __shfl_xor(acc, 2, 32);
    acc += __shfl_xor(acc, 1, 32);

    // lane 0 -> R, 8 -> G, 16 -> B, 24 -> depth (per 32-lane segment)
    const int sub = l & 7;
    if (sub == 0) {
        const int slot = l >> 3;              // 0..3
        if (slot == 3) out_depth[ray] = acc;
        else           out_rgb[ray * 3 + slot] = acc;
    }
}

extern "C" void kernel_launch(void* const* d_in, const int* in_sizes, int n_in,
                              void* d_out, int out_size, void* d_ws, size_t ws_size,
                              hipStream_t stream) {
    const float4* pred4 = (const float4*)d_in[0];   // [B,H,W,32,4] f32
    const float*  tvals = (const float*)d_in[1];    // [B,H,W,32]   f32

    const int total_samples = in_sizes[1];          // 20,480,000 (div by 256)
    const int rays          = total_samples / 32;

    float* out_rgb   = (float*)d_out;
    float* out_depth = (float*)d_out + (size_t)rays * 3;

    const int block = 256;
    const int grid  = total_samples / block;        // 80000
    nerf_render_kernel<<<grid, block, 0, stream>>>(pred4, tvals, out_rgb,
                                                   out_depth);
}